// Round 1
// baseline (821.223 us; speedup 1.0000x reference)
//
#include <hip/hip_runtime.h>
#include <stdint.h>

typedef unsigned short u16;
typedef __bf16 bf16x8 __attribute__((ext_vector_type(8)));
typedef float f32x4 __attribute__((ext_vector_type(4)));

// B=8, N=1024, C=768, H=12, HD=64, FF=2048, M=8192
// out (f32): src[6291456] | scorenet[8000] | y[8000] | attn[100663296]

__device__ __forceinline__ u16 f2bf(float f) {
  union { float f; unsigned u; } v; v.f = f;
  unsigned r = v.u + 0x7fffu + ((v.u >> 16) & 1u);  // RNE
  return (u16)(r >> 16);
}
__device__ __forceinline__ float bf2f(unsigned u) {
  union { unsigned u; float f; } v; v.u = u << 16; return v.f;
}

__device__ __forceinline__ void async16(const void* g, void* l) {
  __builtin_amdgcn_global_load_lds(
      (const __attribute__((address_space(1))) void*)g,
      (__attribute__((address_space(3))) void*)l, 16, 0, 0);
}

__device__ __forceinline__ f32x4 mfma16(bf16x8 a, bf16x8 b, f32x4 c) {
  return __builtin_amdgcn_mfma_f32_16x16x32_bf16(a, b, c, 0, 0, 0);
}

__device__ __forceinline__ float gelu_exact(float x) {
  return 0.5f * x * (1.0f + erff(x * 0.70710678118654752440f));
}

// ---------------- LayerNorm: f32 [8192,768] -> bf16 (+optional f32) --------
__global__ __launch_bounds__(256) void ln_kernel(
    const float* __restrict__ x, const float* __restrict__ g,
    const float* __restrict__ b, u16* __restrict__ obf,
    float* __restrict__ of) {
  const size_t row = blockIdx.x;
  const float* xr = x + row * 768;
  const int t = threadIdx.x;
  const int w = t >> 6, lane = t & 63;
  float v0 = xr[t], v1 = xr[t + 256], v2 = xr[t + 512];
  float s = v0 + v1 + v2;
  float sq = v0 * v0 + v1 * v1 + v2 * v2;
#pragma unroll
  for (int off = 32; off > 0; off >>= 1) {
    s += __shfl_down(s, off);
    sq += __shfl_down(sq, off);
  }
  __shared__ float ss[4], ssq[4];
  if (lane == 0) { ss[w] = s; ssq[w] = sq; }
  __syncthreads();
  s = ss[0] + ss[1] + ss[2] + ss[3];
  sq = ssq[0] + ssq[1] + ssq[2] + ssq[3];
  const float mean = s * (1.0f / 768.0f);
  const float var = sq * (1.0f / 768.0f) - mean * mean;
  const float rstd = rsqrtf(var + 1e-5f);
  float y0 = (v0 - mean) * rstd * g[t] + b[t];
  float y1 = (v1 - mean) * rstd * g[t + 256] + b[t + 256];
  float y2 = (v2 - mean) * rstd * g[t + 512] + b[t + 512];
  obf[row * 768 + t] = f2bf(y0);
  obf[row * 768 + t + 256] = f2bf(y1);
  obf[row * 768 + t + 512] = f2bf(y2);
  if (of) {
    of[row * 768 + t] = y0;
    of[row * 768 + t + 256] = y1;
    of[row * 768 + t + 512] = y2;
  }
}

// ---- merged: 4 weight transposes (f32 [K][N] -> bf16 [N][K]) + copies -----
__device__ __forceinline__ void transpose_tile(float (*tile)[33],
                                               const float* __restrict__ W,
                                               u16* __restrict__ Wt, int K,
                                               int N, int bx, int by) {
  const int n0 = bx * 32, k0 = by * 32;
  const int tx = threadIdx.x, ty = threadIdx.y;  // (32,8)
  for (int r = ty; r < 32; r += 8)
    tile[r][tx] = W[(size_t)(k0 + r) * N + n0 + tx];
  __syncthreads();
  for (int r = ty; r < 32; r += 8)
    Wt[(size_t)(n0 + r) * K + k0 + tx] = f2bf(tile[tx][r]);
}

__global__ void misc_kernel(const float* __restrict__ qkv_w,
                            const float* __restrict__ proj_w,
                            const float* __restrict__ l1_w,
                            const float* __restrict__ l2_w,
                            u16* __restrict__ qkvwT, u16* __restrict__ projwT,
                            u16* __restrict__ l1wT, u16* __restrict__ l2wT,
                            const float* __restrict__ y,
                            const float* __restrict__ sc,
                            float* __restrict__ out) {
  __shared__ float tile[32][33];
  int bid = blockIdx.x;
  if (bid < 1728) { transpose_tile(tile, qkv_w, qkvwT, 768, 2304, bid % 72, bid / 72); return; }
  bid -= 1728;
  if (bid < 576) { transpose_tile(tile, proj_w, projwT, 768, 768, bid % 24, bid / 24); return; }
  bid -= 576;
  if (bid < 1536) { transpose_tile(tile, l1_w, l1wT, 768, 2048, bid % 64, bid / 64); return; }
  bid -= 1536;
  if (bid < 1536) { transpose_tile(tile, l2_w, l2wT, 2048, 768, bid % 24, bid / 24); return; }
  bid -= 1536;
  const int t = threadIdx.y * 32 + threadIdx.x;
  const int i = bid * 256 + t;
  if (i < 8000) {
    out[6291456 + i] = sc[i];
    out[6299456 + i] = y[i];
  }
}

// ------------- V transpose: qkv bf16 -> vt[bh][d][n] ------------------------
__global__ void vt_kernel(const u16* __restrict__ qkv, u16* __restrict__ vt) {
  // grid (32, 2, 96), block (32,8)
  const int bh = blockIdx.z, b = bh / 12, h = bh % 12;
  const int n0 = blockIdx.x * 32, d0 = blockIdx.y * 32;
  __shared__ u16 tile[32][33];
  const u16* Vp = qkv + (size_t)b * 1024 * 2304 + 1536 + h * 64;
  const int tx = threadIdx.x, ty = threadIdx.y;
  for (int r = ty; r < 32; r += 8)
    tile[r][tx] = Vp[(size_t)(n0 + r) * 2304 + d0 + tx];
  __syncthreads();
  u16* Op = vt + (size_t)bh * 64 * 1024;
  for (int r = ty; r < 32; r += 8)
    Op[(size_t)(d0 + r) * 1024 + n0 + tx] = tile[tx][r];
}

// ------------- templated bf16 MFMA GEMM --------------------------------------
// C[M,N] = A[M,K] @ Bt[N,K]^T ; wave grid (4/GN)xGN, per-wave WMxWN m16/n16
// Double-buffered LDS: prefetch of K-tile t+1 is issued BEFORE the ds_read+
// MFMA of tile t, so the global_load_lds latency flies under compute; a
// single __syncthreads per K-step (compiler emits vmcnt(0)+lgkmcnt(0) drain)
// both publishes buf[cur] and makes buf[cur^1] safe to overwrite.
template <int BM, int BN, int GN, int WM, int WN>
__global__ __launch_bounds__(256) void gemm_kernel(
    const u16* __restrict__ A, int lda, const u16* __restrict__ Bt, int ldb,
    const float* __restrict__ bias, const float* __restrict__ res,
    float* __restrict__ outF, u16* __restrict__ outB, int ldc, int K,
    int act) {
  __shared__ u16 As[2][BM * 32];
  __shared__ u16 Bs[2][BN * 32];
  const int tid = threadIdx.x;
  const int w = tid >> 6, lane = tid & 63;
  const size_t mBase = (size_t)blockIdx.y * BM;
  const size_t nBase = (size_t)blockIdx.x * BN;
  const int rq = lane >> 2;       // row within 16-row chunk
  const int k8 = (lane & 3) * 8;  // k-offset of this lane's 16B
  const int wmBase = (w / GN) * (WM * 16);
  const int wnBase = (w % GN) * (WN * 16);
  const int tm = lane & 15, kq = lane >> 4;
  const f32x4 zero = {0.f, 0.f, 0.f, 0.f};
  f32x4 acc[WM][WN];
#pragma unroll
  for (int i = 0; i < WM; i++)
#pragma unroll
    for (int j = 0; j < WN; j++) acc[i][j] = zero;

  // prologue: stage K-tile 0 into buffer 0
#pragma unroll
  for (int c = w; c < BM / 16; c += 4)
    async16(A + (mBase + c * 16 + rq) * lda + k8, &As[0][c * 16 * 32]);
#pragma unroll
  for (int c = w; c < BN / 16; c += 4)
    async16(Bt + (nBase + c * 16 + rq) * ldb + k8, &Bs[0][c * 16 * 32]);

  int cur = 0;
  for (int kt = 0; kt < K; kt += 32) {
    __syncthreads();  // buf[cur] ready; prev iter's ds_reads complete
    if (kt + 32 < K) {
      const int nxt = cur ^ 1;
#pragma unroll
      for (int c = w; c < BM / 16; c += 4)
        async16(A + (mBase + c * 16 + rq) * lda + kt + 32 + k8,
                &As[nxt][c * 16 * 32]);
#pragma unroll
      for (int c = w; c < BN / 16; c += 4)
        async16(Bt + (nBase + c * 16 + rq) * ldb + kt + 32 + k8,
                &Bs[nxt][c * 16 * 32]);
    }
    bf16x8 af[WM], bfv[WN];
#pragma unroll
    for (int i = 0; i < WM; i++)
      af[i] = *(const bf16x8*)&As[cur][(wmBase + i * 16 + tm) * 32 + kq * 8];
#pragma unroll
    for (int j = 0; j < WN; j++)
      bfv[j] = *(const bf16x8*)&Bs[cur][(wnBase + j * 16 + tm) * 32 + kq * 8];
#pragma unroll
    for (int i = 0; i < WM; i++)
#pragma unroll
      for (int j = 0; j < WN; j++) acc[i][j] = mfma16(af[i], bfv[j], acc[i][j]);
    cur ^= 1;
  }

#pragma unroll
  for (int i = 0; i < WM; i++) {
    const size_t row0 = mBase + wmBase + i * 16 + kq * 4;
#pragma unroll
    for (int j = 0; j < WN; j++) {
      const size_t col = nBase + wnBase + j * 16 + tm;
      const float bv = bias ? bias[col] : 0.0f;
#pragma unroll
      for (int r = 0; r < 4; r++) {
        const size_t rr = row0 + r;
        float v = acc[i][j][r] + bv;
        if (act) v = gelu_exact(v);
        if (res) v += res[rr * ldc + col];
        if (outF) outF[rr * ldc + col] = v;
        if (outB) outB[rr * ldc + col] = f2bf(v);
      }
    }
  }
}

// ------------- fused flash attention, two-phase recompute -------------------
// block = (32 Q-rows, bh). Phase 1: S -> exp -> row sums only (registers).
// Phase 2: recompute S, p = exp(s)*rinv, write attn f32 once, P->LDS (bf16,
// swizzled), AV MFMA. All LDS tiles XOR-swizzled (<=2-way bank aliasing).
__global__ __launch_bounds__(256, 3) void flash_kernel(
    const u16* __restrict__ qkv, const u16* __restrict__ vt,
    float* __restrict__ attn, u16* __restrict__ aout) {
  __shared__ u16 Qs[32 * 64];       // 4 KB
  __shared__ u16 KV[2 * 128 * 64];  // 32 KB (ph1: K 256x64; ph2: K|V 128x64)
  __shared__ u16 Ps[32 * 128];      // 8 KB
  __shared__ float psum[4][32];
  __shared__ float rinv[32];
  const int tid = threadIdx.x;
  const int w = tid >> 6, lane = tid & 63;
  const int tm = lane & 15, kq = lane >> 4;
  const int bh = blockIdx.y, b = bh / 12, h = bh % 12;
  const size_t m0 = (size_t)blockIdx.x * 32;
  const u16* Qp = qkv + (size_t)b * 1024 * 2304 + h * 64;
  const u16* Kp = Qp + 768;
  const u16* Vp = vt + (size_t)bh * 64 * 1024;
  float* Ab = attn + ((size_t)bh * 1024 + m0) * 1024;

  // stage Q strip (32x64), swizzled 16B chunks
  {
    const int r = tid >> 3, c = tid & 7;
    *(uint4*)&Qs[r * 64 + ((c ^ (r & 7)) * 8)] =
        *(const uint4*)(Qp + (m0 + r) * 2304 + c * 8);
  }
  __syncthreads();
  // A-fragments (Q) are fixed for the whole kernel
  bf16x8 aq[2][2];
#pragma unroll
  for (int i = 0; i < 2; i++)
#pragma unroll
    for (int k2 = 0; k2 < 2; k2++) {
      const int m = i * 16 + tm;
      aq[i][k2] =
          *(const bf16x8*)&Qs[m * 64 + (((k2 * 4 + kq) ^ (m & 7)) * 8)];
    }

  // ---- phase 1: row sums, K-chunks of 256 ----
  f32x4 rs[2] = {{0.f, 0.f, 0.f, 0.f}, {0.f, 0.f, 0.f, 0.f}};
  for (int cc = 0; cc < 4; ++cc) {
    const int nc = cc * 256;
    __syncthreads();
#pragma unroll
    for (int u = 0; u < 8; ++u) {
      const int idx = u * 256 + tid;
      const int r = idx >> 3, c = idx & 7;
      *(uint4*)&KV[r * 64 + ((c ^ (r & 7)) * 8)] =
          *(const uint4*)(Kp + (size_t)(nc + r) * 2304 + c * 8);
    }
    __syncthreads();
#pragma unroll
    for (int jj = 0; jj < 4; ++jj) {
      const int n = (w * 4 + jj) * 16 + tm;
      bf16x8 bk[2];
#pragma unroll
      for (int k2 = 0; k2 < 2; k2++)
        bk[k2] =
            *(const bf16x8*)&KV[n * 64 + (((k2 * 4 + kq) ^ (n & 7)) * 8)];
#pragma unroll
      for (int i = 0; i < 2; i++) {
        f32x4 s = {0.f, 0.f, 0.f, 0.f};
        s = mfma16(aq[i][0], bk[0], s);
        s = mfma16(aq[i][1], bk[1], s);
#pragma unroll
        for (int r = 0; r < 4; r++) rs[i][r] += __expf(s[r] * 0.125f);
      }
    }
  }
  // reduce row sums across the 16 col-lanes, combine waves via LDS
#pragma unroll
  for (int i = 0; i < 2; i++)
#pragma unroll
    for (int r = 0; r < 4; r++) {
      float v = rs[i][r];
      v += __shfl_xor(v, 1); v += __shfl_xor(v, 2);
      v += __shfl_xor(v, 4); v += __shfl_xor(v, 8);
      if (tm == 0) psum[w][i * 16 + kq * 4 + r] = v;
    }
  __syncthreads();
  if (tid < 32)
    rinv[tid] =
        1.0f / (psum[0][tid] + psum[1][tid] + psum[2][tid] + psum[3][tid]);

  // ---- phase 2: recompute, write attn, AV ----
  const f32x4 zero = {0.f, 0.f, 0.f, 0.f};
  f32x4 oacc[2] = {zero, zero};
  const int mi = w & 1, dp = w >> 1;
  for (int cc = 0; cc < 8; ++cc) {
    const int nc = cc * 128;
    __syncthreads();  // guards KV+Ps reuse (and rinv on first iter)
#pragma unroll
    for (int u = 0; u < 4; ++u) {
      const int idx = u * 256 + tid;
      const int r = idx >> 3, c = idx & 7;
      *(uint4*)&KV[r * 64 + ((c ^ (r & 7)) * 8)] =
          *(const uint4*)(Kp + (size_t)(nc + r) * 2304 + c * 8);
    }
#pragma unroll
    for (int u = 0; u < 4; ++u) {
      const int idx = u * 256 + tid;
      const int d = idx >> 4, c = idx & 15;
      *(uint4*)&KV[8192 + d * 128 + ((c ^ (d & 15)) * 8)] =
          *(const uint4*)(Vp + (size_t)d * 1024 + nc + c * 8);
    }
    __syncthreads();
    // S recompute for this wave's 32 cols; normalize; write attn + Ps
#pragma unroll
    for (int jj = 0; jj < 2; ++jj) {
      const int nb = w * 2 + jj;
      const int n = nb * 16 + tm;
      bf16x8 bk[2];
#pragma unroll
      for (int k2 = 0; k2 < 2; k2++)
        bk[k2] =
            *(const bf16x8*)&KV[n * 64 + (((k2 * 4 + kq) ^ (n & 7)) * 8)];
#pragma unroll
      for (int i = 0; i < 2; i++) {
        f32x4 s = {0.f, 0.f, 0.f, 0.f};
        s = mfma16(aq[i][0], bk[0], s);
        s = mfma16(aq[i][1], bk[1], s);
        const int row = i * 16 + kq * 4;
#pragma unroll
        for (int r = 0; r < 4; r++) {
          const float p = __expf(s[r] * 0.125f) * rinv[row + r];
          Ab[(size_t)(row + r) * 1024 + nc + nb * 16 + tm] = p;
          const int pr = row + r, pn = nb * 16 + tm;
          Ps[pr * 128 + (((pn >> 3) ^ (pr & 7)) * 8) + (pn & 7)] = f2bf(p);
        }
      }
    }
    __syncthreads();
    // AV: wave owns (m-block mi, d-blocks 2*dp, 2*dp+1)
#pragma unroll
    for (int k2 = 0; k2 < 4; ++k2) {
      const int m = mi * 16 + tm;
      const bf16x8 ap =
          *(const bf16x8*)&Ps[m * 128 + (((k2 * 4 + kq) ^ (m & 7)) * 8)];
#pragma unroll
      for (int jd = 0; jd < 2; ++jd) {
        const int d = dp * 32 + jd * 16 + tm;
        const bf16x8 bv = *(const bf16x8*)&KV[8192 + d * 128 +
                                              (((k2 * 4 + kq) ^ (d & 15)) * 8)];
        oacc[jd] = mfma16(ap, bv, oacc[jd]);
      }
    }
  }
  // epilogue: O already normalized
#pragma unroll
  for (int jd = 0; jd < 2; ++jd)
#pragma unroll
    for (int r = 0; r < 4; ++r) {
      const size_t gm = (size_t)b * 1024 + m0 + mi * 16 + kq * 4 + r;
      aout[gm * 768 + h * 64 + dp * 32 + jd * 16 + tm] = f2bf(oacc[jd][r]);
    }
}

extern "C" void kernel_launch(void* const* d_in, const int* in_sizes, int n_in,
                              void* d_out, int out_size, void* d_ws,
                              size_t ws_size, hipStream_t stream) {
  const float* src    = (const float*)d_in[0];
  const float* yin    = (const float*)d_in[1];
  const float* scin   = (const float*)d_in[2];
  const float* pre_g  = (const float*)d_in[3];
  const float* pre_b  = (const float*)d_in[4];
  const float* qkv_w  = (const float*)d_in[5];
  const float* proj_w = (const float*)d_in[6];
  const float* proj_b = (const float*)d_in[7];
  const float* n1_g   = (const float*)d_in[8];
  const float* n1_b   = (const float*)d_in[9];
  const float* l1_w   = (const float*)d_in[10];
  const float* l1_b   = (const float*)d_in[11];
  const float* l2_w   = (const float*)d_in[12];
  const float* l2_b   = (const float*)d_in[13];
  float* outp = (float*)d_out;
  float* attn = outp + 6307456;

  char* ws = (char*)d_ws;
  u16* qkvwT  = (u16*)(ws + 0ull);          // 2304x768
  u16* projwT = (u16*)(ws + 3538944ull);    // 768x768
  u16* l1wT   = (u16*)(ws + 4718592ull);    // 2048x768
  u16* l2wT   = (u16*)(ws + 7864320ull);    // 768x2048
  const size_t P0 = 11010048ull;
  u16* xn   = (u16*)(ws + P0);                 // 8192x768 bf16
  u16* qkv  = (u16*)(ws + P0 + 12582912ull);   // 8192x2304 bf16
  u16* vt   = (u16*)(ws + P0 + 50331648ull);   // 96x64x1024 bf16
  u16* aout = (u16*)(ws + P0 + 62914560ull);   // 8192x768 bf16
  float* src2 = (float*)(ws + P0);                // 8192x768 f32
  u16*  snb   = (u16*)(ws + P0 + 25165824ull);    // 8192x768 bf16
  u16*  hbuf  = (u16*)(ws + P0 + 37748736ull);    // 8192x2048 bf16
  float* snf  = (float*)(ws + P0 + 71303168ull);  // 8192x768 f32

  dim3 tb(32, 8);
  misc_kernel<<<5439, tb, 0, stream>>>(qkv_w, proj_w, l1_w, l2_w, qkvwT,
                                       projwT, l1wT, l2wT, yin, scin, outp);
  ln_kernel<<<8192, 256, 0, stream>>>(src, pre_g, pre_b, xn, nullptr);
  // QKV: [8192,768]@[768,2304] -> bf16
  gemm_kernel<128, 128, 2, 4, 4><<<dim3(18, 64), 256, 0, stream>>>(
      xn, 768, qkvwT, 768, nullptr, nullptr, nullptr, qkv, 2304, 768, 0);
  vt_kernel<<<dim3(32, 2, 96), tb, 0, stream>>>(qkv, vt);
  // fused scores+softmax+AV (writes attn f32 once, aout bf16)
  flash_kernel<<<dim3(32, 96), 256, 0, stream>>>(qkv, vt, attn, aout);
  // proj + residual(src) -> src2 f32
  gemm_kernel<64, 128, 4, 4, 2><<<dim3(6, 128), 256, 0, stream>>>(
      aout, 768, projwT, 768, proj_b, src, src2, nullptr, 768, 768, 0);
  ln_kernel<<<8192, 256, 0, stream>>>(src2, n1_g, n1_b, snb, snf);
  // FFN1 + exact GELU -> bf16
  gemm_kernel<128, 128, 2, 4, 4><<<dim3(16, 64), 256, 0, stream>>>(
      snb, 768, l1wT, 768, l1_b, nullptr, nullptr, hbuf, 2048, 768, 1);
  // FFN2 + residual(src_n) -> out
  gemm_kernel<64, 128, 4, 4, 2><<<dim3(6, 128), 256, 0, stream>>>(
      hbuf, 2048, l2wT, 2048, l2_b, snf, outp, nullptr, 768, 2048, 0);
}

// Round 2
// 807.073 us; speedup vs baseline: 1.0175x; 1.0175x over previous
//
#include <hip/hip_runtime.h>
#include <stdint.h>

typedef unsigned short u16;
typedef __bf16 bf16x8 __attribute__((ext_vector_type(8)));
typedef float f32x4 __attribute__((ext_vector_type(4)));

// B=8, N=1024, C=768, H=12, HD=64, FF=2048, M=8192
// out (f32): src[6291456] | scorenet[8000] | y[8000] | attn[100663296]

__device__ __forceinline__ u16 f2bf(float f) {
  union { float f; unsigned u; } v; v.f = f;
  unsigned r = v.u + 0x7fffu + ((v.u >> 16) & 1u);  // RNE
  return (u16)(r >> 16);
}
__device__ __forceinline__ float bf2f(unsigned u) {
  union { unsigned u; float f; } v; v.u = u << 16; return v.f;
}

__device__ __forceinline__ void async16(const void* g, void* l) {
  __builtin_amdgcn_global_load_lds(
      (const __attribute__((address_space(1))) void*)g,
      (__attribute__((address_space(3))) void*)l, 16, 0, 0);
}

__device__ __forceinline__ f32x4 mfma16(bf16x8 a, bf16x8 b, f32x4 c) {
  return __builtin_amdgcn_mfma_f32_16x16x32_bf16(a, b, c, 0, 0, 0);
}

__device__ __forceinline__ float gelu_exact(float x) {
  return 0.5f * x * (1.0f + erff(x * 0.70710678118654752440f));
}

#define VMCNT(n) asm volatile("s_waitcnt vmcnt(" #n ")" ::: "memory")
#define LGKM0 asm volatile("s_waitcnt lgkmcnt(0)" ::: "memory")
#define SCHED0 __builtin_amdgcn_sched_barrier(0)
#define BAR __builtin_amdgcn_s_barrier()

// ---------------- LayerNorm: f32 [8192,768] -> bf16 (+optional f32) --------
__global__ __launch_bounds__(256) void ln_kernel(
    const float* __restrict__ x, const float* __restrict__ g,
    const float* __restrict__ b, u16* __restrict__ obf,
    float* __restrict__ of) {
  const size_t row = blockIdx.x;
  const float* xr = x + row * 768;
  const int t = threadIdx.x;
  const int w = t >> 6, lane = t & 63;
  float v0 = xr[t], v1 = xr[t + 256], v2 = xr[t + 512];
  float s = v0 + v1 + v2;
  float sq = v0 * v0 + v1 * v1 + v2 * v2;
#pragma unroll
  for (int off = 32; off > 0; off >>= 1) {
    s += __shfl_down(s, off);
    sq += __shfl_down(sq, off);
  }
  __shared__ float ss[4], ssq[4];
  if (lane == 0) { ss[w] = s; ssq[w] = sq; }
  __syncthreads();
  s = ss[0] + ss[1] + ss[2] + ss[3];
  sq = ssq[0] + ssq[1] + ssq[2] + ssq[3];
  const float mean = s * (1.0f / 768.0f);
  const float var = sq * (1.0f / 768.0f) - mean * mean;
  const float rstd = rsqrtf(var + 1e-5f);
  float y0 = (v0 - mean) * rstd * g[t] + b[t];
  float y1 = (v1 - mean) * rstd * g[t + 256] + b[t + 256];
  float y2 = (v2 - mean) * rstd * g[t + 512] + b[t + 512];
  obf[row * 768 + t] = f2bf(y0);
  obf[row * 768 + t + 256] = f2bf(y1);
  obf[row * 768 + t + 512] = f2bf(y2);
  if (of) {
    of[row * 768 + t] = y0;
    of[row * 768 + t + 256] = y1;
    of[row * 768 + t + 512] = y2;
  }
}

// ---- merged: 4 weight transposes (f32 [K][N] -> bf16 [N][K]) + copies -----
__device__ __forceinline__ void transpose_tile(float (*tile)[33],
                                               const float* __restrict__ W,
                                               u16* __restrict__ Wt, int K,
                                               int N, int bx, int by) {
  const int n0 = bx * 32, k0 = by * 32;
  const int tx = threadIdx.x, ty = threadIdx.y;  // (32,8)
  for (int r = ty; r < 32; r += 8)
    tile[r][tx] = W[(size_t)(k0 + r) * N + n0 + tx];
  __syncthreads();
  for (int r = ty; r < 32; r += 8)
    Wt[(size_t)(n0 + r) * K + k0 + tx] = f2bf(tile[tx][r]);
}

__global__ void misc_kernel(const float* __restrict__ qkv_w,
                            const float* __restrict__ proj_w,
                            const float* __restrict__ l1_w,
                            const float* __restrict__ l2_w,
                            u16* __restrict__ qkvwT, u16* __restrict__ projwT,
                            u16* __restrict__ l1wT, u16* __restrict__ l2wT,
                            const float* __restrict__ y,
                            const float* __restrict__ sc,
                            float* __restrict__ out) {
  __shared__ float tile[32][33];
  int bid = blockIdx.x;
  if (bid < 1728) { transpose_tile(tile, qkv_w, qkvwT, 768, 2304, bid % 72, bid / 72); return; }
  bid -= 1728;
  if (bid < 576) { transpose_tile(tile, proj_w, projwT, 768, 768, bid % 24, bid / 24); return; }
  bid -= 576;
  if (bid < 1536) { transpose_tile(tile, l1_w, l1wT, 768, 2048, bid % 64, bid / 64); return; }
  bid -= 1536;
  if (bid < 1536) { transpose_tile(tile, l2_w, l2wT, 2048, 768, bid % 24, bid / 24); return; }
  bid -= 1536;
  const int t = threadIdx.y * 32 + threadIdx.x;
  const int i = bid * 256 + t;
  if (i < 8000) {
    out[6291456 + i] = sc[i];
    out[6299456 + i] = y[i];
  }
}

// ------------- V transpose: qkv bf16 -> vt[bh][d][n] ------------------------
__global__ void vt_kernel(const u16* __restrict__ qkv, u16* __restrict__ vt) {
  // grid (32, 2, 96), block (32,8)
  const int bh = blockIdx.z, b = bh / 12, h = bh % 12;
  const int n0 = blockIdx.x * 32, d0 = blockIdx.y * 32;
  __shared__ u16 tile[32][33];
  const u16* Vp = qkv + (size_t)b * 1024 * 2304 + 1536 + h * 64;
  const int tx = threadIdx.x, ty = threadIdx.y;
  for (int r = ty; r < 32; r += 8)
    tile[r][tx] = Vp[(size_t)(n0 + r) * 2304 + d0 + tx];
  __syncthreads();
  u16* Op = vt + (size_t)bh * 64 * 1024;
  for (int r = ty; r < 32; r += 8)
    Op[(size_t)(d0 + r) * 1024 + n0 + tx] = tile[tx][r];
}

// ------------- templated bf16 MFMA GEMM (2-phase, for N=768 outputs) -------
template <int BM, int BN, int GN, int WM, int WN>
__global__ __launch_bounds__(256) void gemm_kernel(
    const u16* __restrict__ A, int lda, const u16* __restrict__ Bt, int ldb,
    const float* __restrict__ bias, const float* __restrict__ res,
    float* __restrict__ outF, u16* __restrict__ outB, int ldc, int K,
    int act) {
  __shared__ u16 As[2][BM * 32];
  __shared__ u16 Bs[2][BN * 32];
  const int tid = threadIdx.x;
  const int w = tid >> 6, lane = tid & 63;
  const size_t mBase = (size_t)blockIdx.y * BM;
  const size_t nBase = (size_t)blockIdx.x * BN;
  const int rq = lane >> 2;       // row within 16-row chunk
  const int k8 = (lane & 3) * 8;  // k-offset of this lane's 16B
  const int wmBase = (w / GN) * (WM * 16);
  const int wnBase = (w % GN) * (WN * 16);
  const int tm = lane & 15, kq = lane >> 4;
  const f32x4 zero = {0.f, 0.f, 0.f, 0.f};
  f32x4 acc[WM][WN];
#pragma unroll
  for (int i = 0; i < WM; i++)
#pragma unroll
    for (int j = 0; j < WN; j++) acc[i][j] = zero;

  // prologue: stage K-tile 0 into buffer 0
#pragma unroll
  for (int c = w; c < BM / 16; c += 4)
    async16(A + (mBase + c * 16 + rq) * lda + k8, &As[0][c * 16 * 32]);
#pragma unroll
  for (int c = w; c < BN / 16; c += 4)
    async16(Bt + (nBase + c * 16 + rq) * ldb + k8, &Bs[0][c * 16 * 32]);

  int cur = 0;
  for (int kt = 0; kt < K; kt += 32) {
    __syncthreads();  // buf[cur] ready; prev iter's ds_reads complete
    if (kt + 32 < K) {
      const int nxt = cur ^ 1;
#pragma unroll
      for (int c = w; c < BM / 16; c += 4)
        async16(A + (mBase + c * 16 + rq) * lda + kt + 32 + k8,
                &As[nxt][c * 16 * 32]);
#pragma unroll
      for (int c = w; c < BN / 16; c += 4)
        async16(Bt + (nBase + c * 16 + rq) * ldb + kt + 32 + k8,
                &Bs[nxt][c * 16 * 32]);
    }
    bf16x8 af[WM], bfv[WN];
#pragma unroll
    for (int i = 0; i < WM; i++)
      af[i] = *(const bf16x8*)&As[cur][(wmBase + i * 16 + tm) * 32 + kq * 8];
#pragma unroll
    for (int j = 0; j < WN; j++)
      bfv[j] = *(const bf16x8*)&Bs[cur][(wnBase + j * 16 + tm) * 32 + kq * 8];
#pragma unroll
    for (int i = 0; i < WM; i++)
#pragma unroll
      for (int j = 0; j < WN; j++) acc[i][j] = mfma16(af[i], bfv[j], acc[i][j]);
    cur ^= 1;
  }

#pragma unroll
  for (int i = 0; i < WM; i++) {
    const size_t row0 = mBase + wmBase + i * 16 + kq * 4;
#pragma unroll
    for (int j = 0; j < WN; j++) {
      const size_t col = nBase + wnBase + j * 16 + tm;
      const float bv = bias ? bias[col] : 0.0f;
#pragma unroll
      for (int r = 0; r < 4; r++) {
        const size_t rr = row0 + r;
        float v = acc[i][j][r] + bv;
        if (act) v = gelu_exact(v);
        if (res) v += res[rr * ldc + col];
        if (outF) outF[rr * ldc + col] = v;
        if (outB) outB[rr * ldc + col] = f2bf(v);
      }
    }
  }
}

// ------------- 256x256 8-phase GEMM (T1+T2+T3+T4+T5), bf16 out --------------
// C[M,N] = A[M,K] @ Bt[N,K]^T. 512 thr = 8 waves (2M x 4N); per-wave 128x64.
// BK=64; LDS 128 KB double-buffered; per K-step 4 phases, each:
//   {ds_read quad frags | issue 2 staging rounds} -> barrier -> lgkmcnt(0)
//   -> setprio(1) 16xMFMA setprio(0) -> barrier
// Counted vmcnt placed one phase ahead of consumption:
//   staging order: r0-3 = B rows 0/64/128/192; r4-7 = A rows 0/128/64/192.
//   phase 1: vmcnt(4) guarantees r6,r7 (A rows 64-127,192-255) for phases 2,3
//   phase 3: vmcnt(2) guarantees next tile's r0-5 for next phases 0,1
// LDS swizzle (both-sides): chunk' = chunk ^ (row&7); gload_lds writes
// linearly, so the global SOURCE chunk is pre-swizzled (rule #21).
#define QUAD(P)                                                              \
  __builtin_amdgcn_s_setprio(1);                                             \
  _Pragma("unroll") for (int i2 = 0; i2 < 2; ++i2) {                         \
    _Pragma("unroll") for (int j = 0; j < 4; ++j) {                          \
      acc[(P)*2 + i2][j] = mfma16(aF[i2][0], bF[j][0], acc[(P)*2 + i2][j]);  \
      acc[(P)*2 + i2][j] = mfma16(aF[i2][1], bF[j][1], acc[(P)*2 + i2][j]);  \
    }                                                                        \
  }                                                                          \
  __builtin_amdgcn_s_setprio(0);

template <int ACT>
__global__ __launch_bounds__(512, 2) void gemm256_kernel(
    const u16* __restrict__ A, int lda, const u16* __restrict__ Bt, int ldb,
    const float* __restrict__ bias, u16* __restrict__ outB, int ldc, int K,
    int NX, int nwg8) {
  __shared__ u16 As[2][256 * 64];
  __shared__ u16 Bs[2][256 * 64];
  const int tid = threadIdx.x;
  const int w = tid >> 6, lane = tid & 63;
  const int wr = w >> 2, wc = w & 3;        // 2 x 4 wave grid
  const int tm = lane & 15, kq = lane >> 4;
  // T1: bijective XCD swizzle (grid % 8 == 0)
  const int id = blockIdx.x;
  const int wg = (id & 7) * nwg8 + (id >> 3);
  const size_t mBase = (size_t)(wg / NX) * 256;
  const size_t nBase = (size_t)(wg % NX) * 256;
  // staging geometry: 512 thr x 16B = one 64-row x 64-col round (8 KB)
  const int srow = tid >> 3;                 // 0..63
  const int gch = (tid & 7) ^ (srow & 7);    // pre-swizzled global chunk

#define STAGE_B(buf, kt, rb)                                          \
  async16(Bt + (nBase + (rb) + srow) * (size_t)ldb + (kt) + gch * 8,  \
          &Bs[buf][(rb) * 64 + tid * 8])
#define STAGE_A(buf, kt, rb)                                          \
  async16(A + (mBase + (rb) + srow) * (size_t)lda + (kt) + gch * 8,   \
          &As[buf][(rb) * 64 + tid * 8])

  f32x4 acc[8][4];
  const f32x4 zero = {0.f, 0.f, 0.f, 0.f};
#pragma unroll
  for (int i = 0; i < 8; ++i)
#pragma unroll
    for (int j = 0; j < 4; ++j) acc[i][j] = zero;

  // swizzled ds_read of one 16x32 fragment
  auto rdA = [&](int buf, int i, int s) -> bf16x8 {
    const int rl = wr * 128 + i * 16 + tm;
    const int ch = (s * 4 + kq) ^ (rl & 7);
    return *(const bf16x8*)&As[buf][rl * 64 + ch * 8];
  };
  auto rdB = [&](int buf, int j, int s) -> bf16x8 {
    const int rl = wc * 64 + j * 16 + tm;
    const int ch = (s * 4 + kq) ^ (rl & 7);
    return *(const bf16x8*)&Bs[buf][rl * 64 + ch * 8];
  };

  // prologue: stage K-step 0 into buf 0 (rounds r0..r7)
  STAGE_B(0, 0, 0); STAGE_B(0, 0, 64); STAGE_B(0, 0, 128); STAGE_B(0, 0, 192);
  STAGE_A(0, 0, 0); STAGE_A(0, 0, 128); STAGE_A(0, 0, 64); STAGE_A(0, 0, 192);
  VMCNT(2);  // r0-5 resident (B all + A rows 0-63,128-191)
  BAR;

  const int T = K >> 6;
  bf16x8 bF[4][2], aF[2][2];
  for (int t = 0; t < T; ++t) {
    const int cur = t & 1, nxt = cur ^ 1;
    const int kt1 = (t + 1) << 6;
    const bool last = (t == T - 1);
    // ---- phase 0: B all + A quad 0 ----
#pragma unroll
    for (int j = 0; j < 4; ++j) { bF[j][0] = rdB(cur, j, 0); bF[j][1] = rdB(cur, j, 1); }
    aF[0][0] = rdA(cur, 0, 0); aF[0][1] = rdA(cur, 0, 1);
    aF[1][0] = rdA(cur, 1, 0); aF[1][1] = rdA(cur, 1, 1);
    if (!last) { STAGE_B(nxt, kt1, 0); STAGE_B(nxt, kt1, 64); }
    BAR; LGKM0; SCHED0;
    QUAD(0);
    BAR;
    // ---- phase 1: A quad 1; guarantee r6,r7 before phases 2,3 ----
    aF[0][0] = rdA(cur, 2, 0); aF[0][1] = rdA(cur, 2, 1);
    aF[1][0] = rdA(cur, 3, 0); aF[1][1] = rdA(cur, 3, 1);
    if (!last) { STAGE_B(nxt, kt1, 128); STAGE_B(nxt, kt1, 192); VMCNT(4); }
    else { VMCNT(0); }
    BAR; LGKM0; SCHED0;
    QUAD(1);
    BAR;
    // ---- phase 2: A quad 2 ----
    aF[0][0] = rdA(cur, 4, 0); aF[0][1] = rdA(cur, 4, 1);
    aF[1][0] = rdA(cur, 5, 0); aF[1][1] = rdA(cur, 5, 1);
    if (!last) { STAGE_A(nxt, kt1, 0); STAGE_A(nxt, kt1, 128); }
    BAR; LGKM0; SCHED0;
    QUAD(2);
    BAR;
    // ---- phase 3: A quad 3; guarantee next tile r0-5 for next phases 0,1 ----
    aF[0][0] = rdA(cur, 6, 0); aF[0][1] = rdA(cur, 6, 1);
    aF[1][0] = rdA(cur, 7, 0); aF[1][1] = rdA(cur, 7, 1);
    if (!last) { STAGE_A(nxt, kt1, 64); STAGE_A(nxt, kt1, 192); VMCNT(2); }
    BAR; LGKM0; SCHED0;
    QUAD(3);
    BAR;
  }

  // epilogue
#pragma unroll
  for (int i = 0; i < 8; ++i) {
    const size_t row0 = mBase + wr * 128 + i * 16 + kq * 4;
#pragma unroll
    for (int j = 0; j < 4; ++j) {
      const size_t col = nBase + wc * 64 + j * 16 + tm;
      const float bv = bias ? bias[col] : 0.0f;
#pragma unroll
      for (int r = 0; r < 4; ++r) {
        float v = acc[i][j][r] + bv;
        if (ACT) v = gelu_exact(v);
        outB[(row0 + r) * ldc + col] = f2bf(v);
      }
    }
  }
#undef STAGE_A
#undef STAGE_B
}

// ------------- fused flash attention, two-phase recompute -------------------
__global__ __launch_bounds__(256, 3) void flash_kernel(
    const u16* __restrict__ qkv, const u16* __restrict__ vt,
    float* __restrict__ attn, u16* __restrict__ aout) {
  __shared__ u16 Qs[32 * 64];       // 4 KB
  __shared__ u16 KV[2 * 128 * 64];  // 32 KB (ph1: K 256x64; ph2: K|V 128x64)
  __shared__ u16 Ps[32 * 128];      // 8 KB
  __shared__ float psum[4][32];
  __shared__ float rinv[32];
  const int tid = threadIdx.x;
  const int w = tid >> 6, lane = tid & 63;
  const int tm = lane & 15, kq = lane >> 4;
  const int bh = blockIdx.y, b = bh / 12, h = bh % 12;
  const size_t m0 = (size_t)blockIdx.x * 32;
  const u16* Qp = qkv + (size_t)b * 1024 * 2304 + h * 64;
  const u16* Kp = Qp + 768;
  const u16* Vp = vt + (size_t)bh * 64 * 1024;
  float* Ab = attn + ((size_t)bh * 1024 + m0) * 1024;

  // stage Q strip (32x64), swizzled 16B chunks
  {
    const int r = tid >> 3, c = tid & 7;
    *(uint4*)&Qs[r * 64 + ((c ^ (r & 7)) * 8)] =
        *(const uint4*)(Qp + (m0 + r) * 2304 + c * 8);
  }
  __syncthreads();
  // A-fragments (Q) are fixed for the whole kernel
  bf16x8 aq[2][2];
#pragma unroll
  for (int i = 0; i < 2; i++)
#pragma unroll
    for (int k2 = 0; k2 < 2; k2++) {
      const int m = i * 16 + tm;
      aq[i][k2] =
          *(const bf16x8*)&Qs[m * 64 + (((k2 * 4 + kq) ^ (m & 7)) * 8)];
    }

  // ---- phase 1: row sums, K-chunks of 256 ----
  f32x4 rs[2] = {{0.f, 0.f, 0.f, 0.f}, {0.f, 0.f, 0.f, 0.f}};
  for (int cc = 0; cc < 4; ++cc) {
    const int nc = cc * 256;
    __syncthreads();
#pragma unroll
    for (int u = 0; u < 8; ++u) {
      const int idx = u * 256 + tid;
      const int r = idx >> 3, c = idx & 7;
      *(uint4*)&KV[r * 64 + ((c ^ (r & 7)) * 8)] =
          *(const uint4*)(Kp + (size_t)(nc + r) * 2304 + c * 8);
    }
    __syncthreads();
#pragma unroll
    for (int jj = 0; jj < 4; ++jj) {
      const int n = (w * 4 + jj) * 16 + tm;
      bf16x8 bk[2];
#pragma unroll
      for (int k2 = 0; k2 < 2; k2++)
        bk[k2] =
            *(const bf16x8*)&KV[n * 64 + (((k2 * 4 + kq) ^ (n & 7)) * 8)];
#pragma unroll
      for (int i = 0; i < 2; i++) {
        f32x4 s = {0.f, 0.f, 0.f, 0.f};
        s = mfma16(aq[i][0], bk[0], s);
        s = mfma16(aq[i][1], bk[1], s);
#pragma unroll
        for (int r = 0; r < 4; r++) rs[i][r] += __expf(s[r] * 0.125f);
      }
    }
  }
  // reduce row sums across the 16 col-lanes, combine waves via LDS
#pragma unroll
  for (int i = 0; i < 2; i++)
#pragma unroll
    for (int r = 0; r < 4; r++) {
      float v = rs[i][r];
      v += __shfl_xor(v, 1); v += __shfl_xor(v, 2);
      v += __shfl_xor(v, 4); v += __shfl_xor(v, 8);
      if (tm == 0) psum[w][i * 16 + kq * 4 + r] = v;
    }
  __syncthreads();
  if (tid < 32)
    rinv[tid] =
        1.0f / (psum[0][tid] + psum[1][tid] + psum[2][tid] + psum[3][tid]);

  // ---- phase 2: recompute, write attn, AV ----
  const f32x4 zero = {0.f, 0.f, 0.f, 0.f};
  f32x4 oacc[2] = {zero, zero};
  const int mi = w & 1, dp = w >> 1;
  for (int cc = 0; cc < 8; ++cc) {
    const int nc = cc * 128;
    __syncthreads();  // guards KV+Ps reuse (and rinv on first iter)
#pragma unroll
    for (int u = 0; u < 4; ++u) {
      const int idx = u * 256 + tid;
      const int r = idx >> 3, c = idx & 7;
      *(uint4*)&KV[r * 64 + ((c ^ (r & 7)) * 8)] =
          *(const uint4*)(Kp + (size_t)(nc + r) * 2304 + c * 8);
    }
#pragma unroll
    for (int u = 0; u < 4; ++u) {
      const int idx = u * 256 + tid;
      const int d = idx >> 4, c = idx & 15;
      *(uint4*)&KV[8192 + d * 128 + ((c ^ (d & 15)) * 8)] =
          *(const uint4*)(Vp + (size_t)d * 1024 + nc + c * 8);
    }
    __syncthreads();
    // S recompute for this wave's 32 cols; normalize; write attn + Ps
#pragma unroll
    for (int jj = 0; jj < 2; ++jj) {
      const int nb = w * 2 + jj;
      const int n = nb * 16 + tm;
      bf16x8 bk[2];
#pragma unroll
      for (int k2 = 0; k2 < 2; k2++)
        bk[k2] =
            *(const bf16x8*)&KV[n * 64 + (((k2 * 4 + kq) ^ (n & 7)) * 8)];
#pragma unroll
      for (int i = 0; i < 2; i++) {
        f32x4 s = {0.f, 0.f, 0.f, 0.f};
        s = mfma16(aq[i][0], bk[0], s);
        s = mfma16(aq[i][1], bk[1], s);
        const int row = i * 16 + kq * 4;
#pragma unroll
        for (int r = 0; r < 4; r++) {
          const float p = __expf(s[r] * 0.125f) * rinv[row + r];
          Ab[(size_t)(row + r) * 1024 + nc + nb * 16 + tm] = p;
          const int pr = row + r, pn = nb * 16 + tm;
          Ps[pr * 128 + (((pn >> 3) ^ (pr & 7)) * 8) + (pn & 7)] = f2bf(p);
        }
      }
    }
    __syncthreads();
    // AV: wave owns (m-block mi, d-blocks 2*dp, 2*dp+1)
#pragma unroll
    for (int k2 = 0; k2 < 4; ++k2) {
      const int m = mi * 16 + tm;
      const bf16x8 ap =
          *(const bf16x8*)&Ps[m * 128 + (((k2 * 4 + kq) ^ (m & 7)) * 8)];
#pragma unroll
      for (int jd = 0; jd < 2; ++jd) {
        const int d = dp * 32 + jd * 16 + tm;
        const bf16x8 bv = *(const bf16x8*)&KV[8192 + d * 128 +
                                              (((k2 * 4 + kq) ^ (d & 15)) * 8)];
        oacc[jd] = mfma16(ap, bv, oacc[jd]);
      }
    }
  }
  // epilogue: O already normalized
#pragma unroll
  for (int jd = 0; jd < 2; ++jd)
#pragma unroll
    for (int r = 0; r < 4; ++r) {
      const size_t gm = (size_t)b * 1024 + m0 + mi * 16 + kq * 4 + r;
      aout[gm * 768 + h * 64 + dp * 32 + jd * 16 + tm] = f2bf(oacc[jd][r]);
    }
}

extern "C" void kernel_launch(void* const* d_in, const int* in_sizes, int n_in,
                              void* d_out, int out_size, void* d_ws,
                              size_t ws_size, hipStream_t stream) {
  const float* src    = (const float*)d_in[0];
  const float* yin    = (const float*)d_in[1];
  const float* scin   = (const float*)d_in[2];
  const float* pre_g  = (const float*)d_in[3];
  const float* pre_b  = (const float*)d_in[4];
  const float* qkv_w  = (const float*)d_in[5];
  const float* proj_w = (const float*)d_in[6];
  const float* proj_b = (const float*)d_in[7];
  const float* n1_g   = (const float*)d_in[8];
  const float* n1_b   = (const float*)d_in[9];
  const float* l1_w   = (const float*)d_in[10];
  const float* l1_b   = (const float*)d_in[11];
  const float* l2_w   = (const float*)d_in[12];
  const float* l2_b   = (const float*)d_in[13];
  float* outp = (float*)d_out;
  float* attn = outp + 6307456;

  char* ws = (char*)d_ws;
  u16* qkvwT  = (u16*)(ws + 0ull);          // 2304x768
  u16* projwT = (u16*)(ws + 3538944ull);    // 768x768
  u16* l1wT   = (u16*)(ws + 4718592ull);    // 2048x768
  u16* l2wT   = (u16*)(ws + 7864320ull);    // 768x2048
  const size_t P0 = 11010048ull;
  u16* xn   = (u16*)(ws + P0);                 // 8192x768 bf16
  u16* qkv  = (u16*)(ws + P0 + 12582912ull);   // 8192x2304 bf16
  u16* vt   = (u16*)(ws + P0 + 50331648ull);   // 96x64x1024 bf16
  u16* aout = (u16*)(ws + P0 + 62914560ull);   // 8192x768 bf16
  float* src2 = (float*)(ws + P0);                // 8192x768 f32
  u16*  snb   = (u16*)(ws + P0 + 25165824ull);    // 8192x768 bf16
  u16*  hbuf  = (u16*)(ws + P0 + 37748736ull);    // 8192x2048 bf16
  float* snf  = (float*)(ws + P0 + 71303168ull);  // 8192x768 f32

  dim3 tb(32, 8);
  misc_kernel<<<5439, tb, 0, stream>>>(qkv_w, proj_w, l1_w, l2_w, qkvwT,
                                       projwT, l1wT, l2wT, yin, scin, outp);
  ln_kernel<<<8192, 256, 0, stream>>>(src, pre_g, pre_b, xn, nullptr);
  // QKV: [8192,768]@[768,2304] -> bf16 (8-phase 256^2, grid 288 = 32x9)
  gemm256_kernel<0><<<288, 512, 0, stream>>>(xn, 768, qkvwT, 768, nullptr,
                                             qkv, 2304, 768, 9, 36);
  vt_kernel<<<dim3(32, 2, 96), tb, 0, stream>>>(qkv, vt);
  // fused scores+softmax+AV (writes attn f32 once, aout bf16)
  flash_kernel<<<dim3(32, 96), 256, 0, stream>>>(qkv, vt, attn, aout);
  // proj + residual(src) -> src2 f32
  gemm_kernel<64, 128, 4, 4, 2><<<dim3(6, 128), 256, 0, stream>>>(
      aout, 768, projwT, 768, proj_b, src, src2, nullptr, 768, 768, 0);
  ln_kernel<<<8192, 256, 0, stream>>>(src2, n1_g, n1_b, snb, snf);
  // FFN1 + exact GELU -> bf16 (8-phase 256^2, grid 256 = 32x8)
  gemm256_kernel<1><<<256, 512, 0, stream>>>(snb, 768, l1wT, 768, l1_b,
                                             hbuf, 2048, 768, 8, 32);
  // FFN2 + residual(src_n) -> out
  gemm_kernel<64, 128, 4, 4, 2><<<dim3(6, 128), 256, 0, stream>>>(
      hbuf, 2048, l2wT, 2048, l2_b, snf, outp, nullptr, 768, 2048, 0);
}